// Round 3
// baseline (824.620 us; speedup 1.0000x reference)
//
#include <hip/hip_runtime.h>
#include <stdint.h>

#define HW    50176   // 224*224
#define BATCH 16
#define NSEG  196
#define EMB   16
#define MC    16
#define JITTER 0.001f
#define EBLK  14      // emb blocks per batch
#define PXB   3584    // pixels per emb block (50176/14)

// ---------------- threefry2x32 (20 rounds), bit-exact vs JAX ----------------
__host__ __device__ inline void threefry2x32(uint32_t k0, uint32_t k1,
                                             uint32_t x0, uint32_t x1,
                                             uint32_t& o0, uint32_t& o1) {
  uint32_t k2 = k0 ^ k1 ^ 0x1BD11BDAu;
#define TFR(r) { x0 += x1; x1 = (x1 << (r)) | (x1 >> (32 - (r))); x1 ^= x0; }
  x0 += k0; x1 += k1;
  TFR(13) TFR(15) TFR(26) TFR(6)
  x0 += k1; x1 += k2 + 1u;
  TFR(17) TFR(29) TFR(16) TFR(24)
  x0 += k2; x1 += k0 + 2u;
  TFR(13) TFR(15) TFR(26) TFR(6)
  x0 += k0; x1 += k1 + 3u;
  TFR(17) TFR(29) TFR(16) TFR(24)
  x0 += k1; x1 += k2 + 4u;
  TFR(13) TFR(15) TFR(26) TFR(6)
  x0 += k2; x1 += k0 + 5u;
#undef TFR
  o0 = x0; o1 = x1;
}

// XLA ErfInv (f32), Giles polynomial
__device__ inline float erfinv_f32(float x) {
  float w = -log1pf(-x * x);
  float p;
  if (w < 5.0f) {
    w = w - 2.5f;
    p = 2.81022636e-08f;
    p = 3.43273939e-07f + p * w;
    p = -3.5233877e-06f + p * w;
    p = -4.39150654e-06f + p * w;
    p = 0.00021858087f + p * w;
    p = -0.00125372503f + p * w;
    p = -0.00417768164f + p * w;
    p = 0.246640727f + p * w;
    p = 1.50140941f + p * w;
  } else {
    w = sqrtf(w) - 3.0f;
    p = -0.000200214257f;
    p = 0.000100950558f + p * w;
    p = 0.00134934322f + p * w;
    p = -0.00367342844f + p * w;
    p = 0.00573950773f + p * w;
    p = -0.0076224613f + p * w;
    p = 0.00943887047f + p * w;
    p = 1.00167406f + p * w;
    p = 2.83297682f + p * w;
  }
  return p * x;
}

__device__ inline float bits_to_f01(uint32_t bits) {
  uint32_t fb = (bits >> 9) | 0x3F800000u;
  return __uint_as_float(fb) - 1.0f;
}

// ---------------- K1: emb + pixel_probs + per-block partial sums -----------
// partial layout: [b*EBLK+bb][17][196]  (j-major, g coalesced)
__global__ __launch_bounds__(256) void emb_kernel(
    const float* __restrict__ x, const int* __restrict__ groups,
    const float* __restrict__ Wc, const float* __restrict__ bc,
    float* __restrict__ partial, float* __restrict__ pixel_probs) {
  __shared__ float lsum[NSEG * 17];
  int b = blockIdx.x / EBLK;
  int blk = blockIdx.x % EBLK;
  int tid = threadIdx.x;
  for (int i = tid; i < NSEG * 17; i += 256) lsum[i] = 0.0f;
  __syncthreads();
  const float* xb = x + (size_t)b * 3 * HW;
  for (int k = 0; k < PXB / 256; ++k) {
    int p = blk * PXB + k * 256 + tid;
    float x0 = xb[p], x1 = xb[HW + p], x2 = xb[2 * HW + p];
    int g = groups[b * HW + p];
    float* dst = lsum + g * 17;
#pragma unroll
    for (int j = 0; j < EMB; ++j) {
      float e = Wc[j * 3 + 0] * x0 + Wc[j * 3 + 1] * x1;
      e = e + Wc[j * 3 + 2] * x2 + bc[j];
      if (j == 0) pixel_probs[b * HW + p] = 1.0f / (1.0f + expf(-e));
      atomicAdd(&dst[j], e);
    }
    atomicAdd(&dst[16], 1.0f);
  }
  __syncthreads();
  // transposed coalesced flush (no global atomics)
  float* pb = partial + (size_t)blockIdx.x * (17 * NSEG);
  if (tid < NSEG) {
#pragma unroll
    for (int j = 0; j < 17; ++j) pb[j * NSEG + tid] = lsum[tid * 17 + j];
  }
}

// ---------------- K2: stats — mu, group_probs, G (column-major) ------------
__global__ __launch_bounds__(256) void stats_kernel(
    const float* __restrict__ partial, float* __restrict__ mu_ws,
    float* __restrict__ group_probs, float* __restrict__ Gc /* [B][15][196] */) {
  int b = blockIdx.x;
  int i = threadIdx.x;
  if (i >= NSEG) return;
  float acc[17];
#pragma unroll
  for (int j = 0; j < 17; ++j) acc[j] = 0.0f;
  for (int bb = 0; bb < EBLK; ++bb) {
    const float* pb = partial + (size_t)(b * EBLK + bb) * (17 * NSEG);
#pragma unroll
    for (int j = 0; j < 17; ++j) acc[j] += pb[j * NSEG + i];
  }
  float denom = fmaxf(acc[16], 1.0f);
  float m = acc[0] / denom;
  mu_ws[b * NSEG + i] = m;
  group_probs[b * NSEG + i] = 1.0f / (1.0f + expf(-m));
#pragma unroll
  for (int j = 0; j < 15; ++j)
    Gc[((size_t)b * 15 + j) * NSEG + i] = acc[j + 1] / denom;
}

// ---------------- K3: sigma = G G^T + jitter*I (tiled) ---------------------
__global__ __launch_bounds__(256) void sigma_kernel(
    const float* __restrict__ Gc, float* __restrict__ sigma_out) {
  int b = blockIdx.x / 7;
  int tile = blockIdx.x % 7;
  int tid = threadIdx.x;
  __shared__ float ge[15][NSEG];
  if (tid < NSEG) {
#pragma unroll
    for (int j = 0; j < 15; ++j) ge[j][tid] = Gc[((size_t)b * 15 + j) * NSEG + tid];
  }
  __syncthreads();
  if (tid >= NSEG) return;
  int t = tid;
  for (int r = 0; r < 28; ++r) {
    int s = tile * 28 + r;
    float acc = 0.0f;
#pragma unroll
    for (int j = 0; j < 15; ++j) acc = fmaf(ge[j][s], ge[j][t], acc);
    if (s == t) acc += JITTER;
    sigma_out[((size_t)b * NSEG + s) * NSEG + t] = acc;
  }
}

// ---------------- K4: fused rng + low-rank Cholesky + L@eps + hard ---------
// sigma = jitter*I + G G^T.  Schur invariant keeps only G (rank 15) as state:
//   d = sqrt(j + |g_k|^2); L[i,k] = g_i.g_k/d; g_i -= beta (g_i.g_k) g_k,
//   beta = 1/(d(d+sqrt(j))).
// 4 waves/block: each wave replicates the g-recurrence (registers, shfl
// broadcast, no barriers) and owns a 4-wide MC slice.  Rows retire: slot s
// (rows 64s..64s+63) is dead for k >= 64(s+1) -> s-loop starts at k>>6.
// eps generated into LDS in the prologue; logistic noise in the epilogue.
__global__ __launch_bounds__(256, 1) void cholmc_kernel(
    const float* __restrict__ Gc, const float* __restrict__ mu,
    uint32_t kg0, uint32_t kg1, uint32_t ku0, uint32_t ku1,
    float* __restrict__ hard) {
  int b = blockIdx.x;
  int tid = threadIdx.x;
  int lane = tid & 63;
  int wave = tid >> 6;
  __shared__ float eps_lds[NSEG * MC];  // 12.25 KB

  // prologue: eps = sqrt(2)*erfinv(bits) straight into LDS
  for (int t = tid; t < NSEG * MC; t += 256) {
    uint32_t a0, a1;
    threefry2x32(kg0, kg1, 0u, (uint32_t)(b * NSEG * MC + t), a0, a1);
    float f = bits_to_f01(a0 ^ a1);
    const float lo = -0.99999994f;  // nextafter(-1,0)
    float u = fmaxf(lo, f * (1.0f - lo) + lo);
    eps_lds[t] = 1.4142135623730951f * erfinv_f32(u);
  }

  float g[4][15];
  float acc[4][4];
#pragma unroll
  for (int s = 0; s < 4; ++s) {
    int i = s * 64 + lane;
#pragma unroll
    for (int j = 0; j < 15; ++j)
      g[s][j] = (i < NSEG) ? Gc[((size_t)b * 15 + j) * NSEG + i] : 0.0f;
#pragma unroll
    for (int q = 0; q < 4; ++q) acc[s][q] = 0.0f;
  }
  __syncthreads();

  const float sj = 0.031622776601683794f;  // sqrt(jitter)
  for (int k = 0; k < NSEG; ++k) {
    int owner = k & 63;
    int s0 = k >> 6;  // wave-uniform; slots < s0 retired
    float gk[15];
    switch (s0) {
      case 0:
#pragma unroll
        for (int j = 0; j < 15; ++j) gk[j] = __shfl(g[0][j], owner, 64);
        break;
      case 1:
#pragma unroll
        for (int j = 0; j < 15; ++j) gk[j] = __shfl(g[1][j], owner, 64);
        break;
      case 2:
#pragma unroll
        for (int j = 0; j < 15; ++j) gk[j] = __shfl(g[2][j], owner, 64);
        break;
      default:
#pragma unroll
        for (int j = 0; j < 15; ++j) gk[j] = __shfl(g[3][j], owner, 64);
        break;
    }
    float nrm = 0.0f;
#pragma unroll
    for (int j = 0; j < 15; ++j) nrm = fmaf(gk[j], gk[j], nrm);
    float dd = sqrtf(JITTER + nrm);
    float invd = 1.0f / dd;                // precise IEEE divide
    float beta = 1.0f / (dd * (dd + sj));  // stable Schur downdate scale
    const float4 ekv = *(const float4*)(eps_lds + k * MC + wave * 4);
    float ek[4] = {ekv.x, ekv.y, ekv.z, ekv.w};
    for (int s = s0; s < 4; ++s) {
      int i = s * 64 + lane;
      float dot = 0.0f;
#pragma unroll
      for (int j = 0; j < 15; ++j) dot = fmaf(g[s][j], gk[j], dot);
      float lik = (i == k) ? dd : dot * invd;
      float w = (i >= k && i < NSEG) ? lik : 0.0f;
#pragma unroll
      for (int q = 0; q < 4; ++q) acc[s][q] = fmaf(w, ek[q], acc[s][q]);
      float bd = beta * dot;
#pragma unroll
      for (int j = 0; j < 15; ++j) g[s][j] = fmaf(-bd, gk[j], g[s][j]);
    }
  }

  // epilogue: hard = (mu + L@eps + logistic) > 0, this wave's m-slice
#pragma unroll
  for (int s = 0; s < 4; ++s) {
    int i = s * 64 + lane;
    if (i < NSEG) {
      float mui = mu[b * NSEG + i];
      float4 outv;
      float* op = (float*)&outv;
#pragma unroll
      for (int q = 0; q < 4; ++q) {
        int m = wave * 4 + q;
        uint32_t a0, a1;
        threefry2x32(ku0, ku1, 0u, (uint32_t)(b * NSEG * MC + i * MC + m), a0, a1);
        float f = bits_to_f01(a0 ^ a1);
        const float mn = 1e-6f;
        const float mx = (float)(1.0 - 1e-6);
        float uu = fmaxf(mn, f * (mx - mn) + mn);
        float lg = logf(uu) - log1pf(-uu);
        float z = mui + acc[s][q] + lg;
        op[q] = (z > 0.0f) ? 1.0f : 0.0f;
      }
      *(float4*)(hard + ((size_t)b * NSEG + i) * MC + wave * 4) = outv;
    }
  }
}

// ---------------- K5: mask gather, one float4 per thread -------------------
__global__ __launch_bounds__(256) void mask_kernel(
    const int* __restrict__ groups, const float* __restrict__ hard,
    float4* __restrict__ out) {
  int f = blockIdx.x * blockDim.x + threadIdx.x;  // float4 index
  if (f >= BATCH * 3 * HW * 4) return;
  int pix = f >> 2;          // (b*3+c)*HW + p
  int q = f & 3;
  int b = pix / (3 * HW);
  int p = pix % HW;
  int g = groups[b * HW + p];
  out[f] = ((const float4*)hard)[(b * NSEG + g) * 4 + q];
}

extern "C" void kernel_launch(void* const* d_in, const int* in_sizes, int n_in,
                              void* d_out, int out_size, void* d_ws, size_t ws_size,
                              hipStream_t stream) {
  const float* x = (const float*)d_in[0];
  const int* groups = (const int*)d_in[1];
  const float* Wc = (const float*)d_in[2];
  const float* bc = (const float*)d_in[3];

  float* out = (float*)d_out;
  float* mask_out = out;                         // 38,535,168
  float* gp_out = out + 38535168;                //      3,136
  float* pp_out = gp_out + 3136;                 //    802,816
  float* sig_out = pp_out + 802816;              //    614,656

  float* ws = (float*)d_ws;
  float* partial = ws;                           // 224*3332 = 746,368
  float* mu_ws = ws + 746368;                    //   3,136
  float* Gc    = ws + 749504;                    //  47,040  (tot 3.19 MB)
  float* hard  = ws;                             // 50,176 — reuses dead partial

  emb_kernel<<<BATCH * EBLK, 256, 0, stream>>>(x, groups, Wc, bc, partial, pp_out);
  stats_kernel<<<BATCH, 256, 0, stream>>>(partial, mu_ws, gp_out, Gc);
  sigma_kernel<<<BATCH * 7, 256, 0, stream>>>(Gc, sig_out);

  uint32_t kg0, kg1, ku0, ku1;
  threefry2x32(0u, 42u, 0u, 0u, kg0, kg1);
  threefry2x32(0u, 42u, 0u, 1u, ku0, ku1);

  cholmc_kernel<<<BATCH, 256, 0, stream>>>(Gc, mu_ws, kg0, kg1, ku0, ku1, hard);
  mask_kernel<<<(BATCH * 3 * HW * 4 + 255) / 256, 256, 0, stream>>>(
      groups, hard, (float4*)mask_out);
}

// Round 5
// 387.812 us; speedup vs baseline: 2.1263x; 2.1263x over previous
//
#include <hip/hip_runtime.h>
#include <stdint.h>

#define HW    50176   // 224*224
#define BATCH 16
#define NSEG  196
#define EMB   16
#define MC    16
#define JITTER 0.001f
#define EBLK  14      // emb blocks per batch
#define PXB   3584    // pixels per emb block (50176/14)

typedef float vfloat4 __attribute__((ext_vector_type(4)));  // native vec for nontemporal builtins

// ---------------- threefry2x32 (20 rounds), bit-exact vs JAX ----------------
__host__ __device__ inline void threefry2x32(uint32_t k0, uint32_t k1,
                                             uint32_t x0, uint32_t x1,
                                             uint32_t& o0, uint32_t& o1) {
  uint32_t k2 = k0 ^ k1 ^ 0x1BD11BDAu;
#define TFR(r) { x0 += x1; x1 = (x1 << (r)) | (x1 >> (32 - (r))); x1 ^= x0; }
  x0 += k0; x1 += k1;
  TFR(13) TFR(15) TFR(26) TFR(6)
  x0 += k1; x1 += k2 + 1u;
  TFR(17) TFR(29) TFR(16) TFR(24)
  x0 += k2; x1 += k0 + 2u;
  TFR(13) TFR(15) TFR(26) TFR(6)
  x0 += k0; x1 += k1 + 3u;
  TFR(17) TFR(29) TFR(16) TFR(24)
  x0 += k1; x1 += k2 + 4u;
  TFR(13) TFR(15) TFR(26) TFR(6)
  x0 += k2; x1 += k0 + 5u;
#undef TFR
  o0 = x0; o1 = x1;
}

// XLA ErfInv (f32), Giles polynomial
__device__ inline float erfinv_f32(float x) {
  float w = -log1pf(-x * x);
  float p;
  if (w < 5.0f) {
    w = w - 2.5f;
    p = 2.81022636e-08f;
    p = 3.43273939e-07f + p * w;
    p = -3.5233877e-06f + p * w;
    p = -4.39150654e-06f + p * w;
    p = 0.00021858087f + p * w;
    p = -0.00125372503f + p * w;
    p = -0.00417768164f + p * w;
    p = 0.246640727f + p * w;
    p = 1.50140941f + p * w;
  } else {
    w = sqrtf(w) - 3.0f;
    p = -0.000200214257f;
    p = 0.000100950558f + p * w;
    p = 0.00134934322f + p * w;
    p = -0.00367342844f + p * w;
    p = 0.00573950773f + p * w;
    p = -0.0076224613f + p * w;
    p = 0.00943887047f + p * w;
    p = 1.00167406f + p * w;
    p = 2.83297682f + p * w;
  }
  return p * x;
}

__device__ inline float bits_to_f01(uint32_t bits) {
  uint32_t fb = (bits >> 9) | 0x3F800000u;
  return __uint_as_float(fb) - 1.0f;
}

// ---------------- K1: emb + pixel_probs + per-block partial sums -----------
// partial layout: [b*EBLK+bb][17][196]  (j-major, g coalesced)
__global__ __launch_bounds__(256) void emb_kernel(
    const float* __restrict__ x, const int* __restrict__ groups,
    const float* __restrict__ Wc, const float* __restrict__ bc,
    float* __restrict__ partial, float* __restrict__ pixel_probs) {
  __shared__ float lsum[NSEG * 17];
  int b = blockIdx.x / EBLK;
  int blk = blockIdx.x % EBLK;
  int tid = threadIdx.x;
  for (int i = tid; i < NSEG * 17; i += 256) lsum[i] = 0.0f;
  __syncthreads();
  const float* xb = x + (size_t)b * 3 * HW;
  for (int k = 0; k < PXB / 256; ++k) {
    int p = blk * PXB + k * 256 + tid;
    float x0 = xb[p], x1 = xb[HW + p], x2 = xb[2 * HW + p];
    int g = groups[b * HW + p];
    float* dst = lsum + g * 17;
#pragma unroll
    for (int j = 0; j < EMB; ++j) {
      float e = Wc[j * 3 + 0] * x0 + Wc[j * 3 + 1] * x1;
      e = e + Wc[j * 3 + 2] * x2 + bc[j];
      if (j == 0) pixel_probs[b * HW + p] = 1.0f / (1.0f + expf(-e));
      atomicAdd(&dst[j], e);
    }
    atomicAdd(&dst[16], 1.0f);
  }
  __syncthreads();
  // transposed coalesced flush (no global atomics)
  float* pb = partial + (size_t)blockIdx.x * (17 * NSEG);
  if (tid < NSEG) {
#pragma unroll
    for (int j = 0; j < 17; ++j) pb[j * NSEG + tid] = lsum[tid * 17 + j];
  }
}

// ---------------- K2: stats — mu, group_probs, G (column-major) ------------
__global__ __launch_bounds__(256) void stats_kernel(
    const float* __restrict__ partial, float* __restrict__ mu_ws,
    float* __restrict__ group_probs, float* __restrict__ Gc /* [B][15][196] */) {
  int b = blockIdx.x;
  int i = threadIdx.x;
  if (i >= NSEG) return;
  float acc[17];
#pragma unroll
  for (int j = 0; j < 17; ++j) acc[j] = 0.0f;
  for (int bb = 0; bb < EBLK; ++bb) {
    const float* pb = partial + (size_t)(b * EBLK + bb) * (17 * NSEG);
#pragma unroll
    for (int j = 0; j < 17; ++j) acc[j] += pb[j * NSEG + i];
  }
  float denom = fmaxf(acc[16], 1.0f);
  float m = acc[0] / denom;
  mu_ws[b * NSEG + i] = m;
  group_probs[b * NSEG + i] = 1.0f / (1.0f + expf(-m));
#pragma unroll
  for (int j = 0; j < 15; ++j)
    Gc[((size_t)b * 15 + j) * NSEG + i] = acc[j + 1] / denom;
}

// ---------------- K3: sigma = G G^T + jitter*I (tiled) ---------------------
__global__ __launch_bounds__(256) void sigma_kernel(
    const float* __restrict__ Gc, float* __restrict__ sigma_out) {
  int b = blockIdx.x / 7;
  int tile = blockIdx.x % 7;
  int tid = threadIdx.x;
  __shared__ float ge[15][NSEG];
  if (tid < NSEG) {
#pragma unroll
    for (int j = 0; j < 15; ++j) ge[j][tid] = Gc[((size_t)b * 15 + j) * NSEG + tid];
  }
  __syncthreads();
  if (tid >= NSEG) return;
  int t = tid;
  for (int r = 0; r < 28; ++r) {
    int s = tile * 28 + r;
    float acc = 0.0f;
#pragma unroll
    for (int j = 0; j < 15; ++j) acc = fmaf(ge[j][s], ge[j][t], acc);
    if (s == t) acc += JITTER;
    sigma_out[((size_t)b * NSEG + s) * NSEG + t] = acc;
  }
}

// ---------------- K4: fused rng + low-rank Cholesky + L@eps + hard ---------
// sigma = jitter*I + G G^T.  Schur invariant keeps only G (rank 15) as state:
//   d = sqrt(j + |g_k|^2); L[i,k] = g_i.g_k/d; g_i -= beta (g_i.g_k) g_k,
//   beta = 1/(d(d+sqrt(j))).
// 4 waves/block: each wave replicates the g-recurrence (registers, shfl
// broadcast, no barriers) and owns a 4-wide MC slice.  Rows retire: slot s
// is dead for k >= 64(s+1).  CRITICAL: the s-loop must be unrolled with
// COMPILE-TIME s (guard inside) — a runtime lower bound makes g[s][*]
// dynamically indexed and the compiler demotes it to scratch
// (round-3 regression: VGPR 36, +1.5 MB spill traffic, 575 us).
__global__ __launch_bounds__(256, 1) void cholmc_kernel(
    const float* __restrict__ Gc, const float* __restrict__ mu,
    uint32_t kg0, uint32_t kg1, uint32_t ku0, uint32_t ku1,
    float* __restrict__ hard) {
  int b = blockIdx.x;
  int tid = threadIdx.x;
  int lane = tid & 63;
  int wave = tid >> 6;
  __shared__ float eps_lds[NSEG * MC];  // 12.25 KB

  // prologue: eps = sqrt(2)*erfinv(bits) straight into LDS
  for (int t = tid; t < NSEG * MC; t += 256) {
    uint32_t a0, a1;
    threefry2x32(kg0, kg1, 0u, (uint32_t)(b * NSEG * MC + t), a0, a1);
    float f = bits_to_f01(a0 ^ a1);
    const float lo = -0.99999994f;  // nextafter(-1,0)
    float u = fmaxf(lo, f * (1.0f - lo) + lo);
    eps_lds[t] = 1.4142135623730951f * erfinv_f32(u);
  }

  float g[4][15];
  float acc[4][4];
#pragma unroll
  for (int s = 0; s < 4; ++s) {
    int i = s * 64 + lane;
#pragma unroll
    for (int j = 0; j < 15; ++j)
      g[s][j] = (i < NSEG) ? Gc[((size_t)b * 15 + j) * NSEG + i] : 0.0f;
#pragma unroll
    for (int q = 0; q < 4; ++q) acc[s][q] = 0.0f;
  }
  __syncthreads();

  const float sj = 0.031622776601683794f;  // sqrt(jitter)
  for (int k = 0; k < NSEG; ++k) {
    int owner = k & 63;
    int s0 = k >> 6;  // wave-uniform; slots < s0 retired
    float gk[15];
    switch (s0) {
      case 0:
#pragma unroll
        for (int j = 0; j < 15; ++j) gk[j] = __shfl(g[0][j], owner, 64);
        break;
      case 1:
#pragma unroll
        for (int j = 0; j < 15; ++j) gk[j] = __shfl(g[1][j], owner, 64);
        break;
      case 2:
#pragma unroll
        for (int j = 0; j < 15; ++j) gk[j] = __shfl(g[2][j], owner, 64);
        break;
      default:
#pragma unroll
        for (int j = 0; j < 15; ++j) gk[j] = __shfl(g[3][j], owner, 64);
        break;
    }
    float nrm = 0.0f;
#pragma unroll
    for (int j = 0; j < 15; ++j) nrm = fmaf(gk[j], gk[j], nrm);
    float dd = sqrtf(JITTER + nrm);
    float invd = 1.0f / dd;                // precise IEEE divide
    float beta = 1.0f / (dd * (dd + sj));  // stable Schur downdate scale
    const float4 ekv = *(const float4*)(eps_lds + k * MC + wave * 4);
    float ek[4] = {ekv.x, ekv.y, ekv.z, ekv.w};
#pragma unroll
    for (int s = 0; s < 4; ++s) {      // compile-time s; retirement guard inside
      if (s >= s0) {                   // wave-uniform branch
        int i = s * 64 + lane;
        float dot = 0.0f;
#pragma unroll
        for (int j = 0; j < 15; ++j) dot = fmaf(g[s][j], gk[j], dot);
        float lik = (i == k) ? dd : dot * invd;
        float w = (i >= k && i < NSEG) ? lik : 0.0f;
#pragma unroll
        for (int q = 0; q < 4; ++q) acc[s][q] = fmaf(w, ek[q], acc[s][q]);
        float bd = beta * dot;
#pragma unroll
        for (int j = 0; j < 15; ++j) g[s][j] = fmaf(-bd, gk[j], g[s][j]);
      }
    }
  }

  // epilogue: hard = (mu + L@eps + logistic) > 0, this wave's m-slice
#pragma unroll
  for (int s = 0; s < 4; ++s) {
    int i = s * 64 + lane;
    if (i < NSEG) {
      float mui = mu[b * NSEG + i];
      float4 outv;
      float* op = (float*)&outv;
#pragma unroll
      for (int q = 0; q < 4; ++q) {
        int m = wave * 4 + q;
        uint32_t a0, a1;
        threefry2x32(ku0, ku1, 0u, (uint32_t)(b * NSEG * MC + i * MC + m), a0, a1);
        float f = bits_to_f01(a0 ^ a1);
        const float mn = 1e-6f;
        const float mx = (float)(1.0 - 1e-6);
        float uu = fmaxf(mn, f * (mx - mn) + mn);
        float lg = logf(uu) - log1pf(-uu);
        float z = mui + acc[s][q] + lg;
        op[q] = (z > 0.0f) ? 1.0f : 0.0f;
      }
      *(float4*)(hard + ((size_t)b * NSEG + i) * MC + wave * 4) = outv;
    }
  }
}

// ---------------- K5: mask gather, one float4 per thread -------------------
__global__ __launch_bounds__(256) void mask_kernel(
    const int* __restrict__ groups, const float* __restrict__ hard,
    vfloat4* __restrict__ out) {
  int f = blockIdx.x * blockDim.x + threadIdx.x;  // float4 index
  if (f >= BATCH * 3 * HW * 4) return;
  int pix = f >> 2;          // (b*3+c)*HW + p
  int q = f & 3;
  int b = pix / (3 * HW);
  int p = pix % HW;
  int g = groups[b * HW + p];
  vfloat4 v = ((const vfloat4*)hard)[(b * NSEG + g) * 4 + q];
  __builtin_nontemporal_store(v, out + f);  // 154 MB never re-read: skip L2 alloc
}

extern "C" void kernel_launch(void* const* d_in, const int* in_sizes, int n_in,
                              void* d_out, int out_size, void* d_ws, size_t ws_size,
                              hipStream_t stream) {
  const float* x = (const float*)d_in[0];
  const int* groups = (const int*)d_in[1];
  const float* Wc = (const float*)d_in[2];
  const float* bc = (const float*)d_in[3];

  float* out = (float*)d_out;
  float* mask_out = out;                         // 38,535,168
  float* gp_out = out + 38535168;                //      3,136
  float* pp_out = gp_out + 3136;                 //    802,816
  float* sig_out = pp_out + 802816;              //    614,656

  float* ws = (float*)d_ws;
  float* partial = ws;                           // 224*3332 = 746,368
  float* mu_ws = ws + 746368;                    //   3,136
  float* Gc    = ws + 749504;                    //  47,040  (tot 3.19 MB)
  float* hard  = ws;                             // 50,176 — reuses dead partial

  emb_kernel<<<BATCH * EBLK, 256, 0, stream>>>(x, groups, Wc, bc, partial, pp_out);
  stats_kernel<<<BATCH, 256, 0, stream>>>(partial, mu_ws, gp_out, Gc);
  sigma_kernel<<<BATCH * 7, 256, 0, stream>>>(Gc, sig_out);

  uint32_t kg0, kg1, ku0, ku1;
  threefry2x32(0u, 42u, 0u, 0u, kg0, kg1);
  threefry2x32(0u, 42u, 0u, 1u, ku0, ku1);

  cholmc_kernel<<<BATCH, 256, 0, stream>>>(Gc, mu_ws, kg0, kg1, ku0, ku1, hard);
  mask_kernel<<<(BATCH * 3 * HW * 4 + 255) / 256, 256, 0, stream>>>(
      groups, hard, (vfloat4*)mask_out);
}